// Round 10
// baseline (55.938 us; speedup 1.0000x reference)
//
#include <hip/hip_runtime.h>
#include <hip/hip_bf16.h>
#include <math.h>

// SpatialAxialAttention: B*T=2, H=W=16, dim=1024, HEADS=16, DIM_HEAD=64, K=144
#define BTN   2
#define NH    16
#define SEQ   256
#define DH    64
#define DIMF  1024
#define KTOP  144
#define QT    16
#define PI_F  3.14159265358979323846f

typedef _Float16 half8 __attribute__((ext_vector_type(8)));
typedef _Float16 half4v __attribute__((ext_vector_type(4)));
typedef float f32x4 __attribute__((ext_vector_type(4)));

#define GLDS(src, dst) __builtin_amdgcn_global_load_lds( \
        (const __attribute__((address_space(1))) void*)(src), \
        (__attribute__((address_space(3))) void*)(dst), 16, 0, 0)

// ---------------------------------------------------------------------------
// fp32 -> fp16 conversion for x, w_qkv, w_out
// ---------------------------------------------------------------------------
#define N0Q (524288 / 4)
#define N1Q (3145728 / 4)
#define N2Q (1048576 / 4)
__global__ __launch_bounds__(256)
void cvt3_kernel(const float* __restrict__ a, const float* __restrict__ b,
                 const float* __restrict__ c,
                 _Float16* __restrict__ da, _Float16* __restrict__ db,
                 _Float16* __restrict__ dc)
{
    int q = blockIdx.x * 256 + threadIdx.x;
    const float* s; _Float16* d; int off;
    if (q < N0Q)            { s = a; d = da; off = q; }
    else if (q < N0Q + N1Q) { s = b; d = db; off = q - N0Q; }
    else                    { s = c; d = dc; off = q - (N0Q + N1Q); }
    const float4 v = *(const float4*)(s + (size_t)off * 4);
    half4v h;
    h[0] = (_Float16)v.x; h[1] = (_Float16)v.y;
    h[2] = (_Float16)v.z; h[3] = (_Float16)v.w;
    *(half4v*)(d + (size_t)off * 4) = h;
}

// ---------------------------------------------------------------------------
// fp16 MFMA NT-GEMM, DOUBLE-BUFFERED (T3 minimum 2-phase):
// stage tile t+1 into buf^1 BEFORE computing tile t from buf, one
// __syncthreads (vmcnt drain) per K-tile -> next-tile global latency hides
// under current-tile ds_read+MFMA. 64x64 tile, BK=64, 4 waves, 2x2 frags.
// MODE 0: epilogue splits qkv, RoPE on q,k -> fp16 (bt,head,s,d);
//         v -> fp16 TRANSPOSED (bt,head,d,s). MODE 1: +bias fp32 store.
// ---------------------------------------------------------------------------
template <int MODE>
__global__ __launch_bounds__(256)
void gemm_dbuf_kernel(const _Float16* __restrict__ A, const _Float16* __restrict__ B,
                      int N,
                      _Float16* __restrict__ qb, _Float16* __restrict__ kb,
                      _Float16* __restrict__ vb,
                      const float* __restrict__ bias, float* __restrict__ out)
{
    __shared__ __align__(16) _Float16 As[2][64 * 64];
    __shared__ __align__(16) _Float16 Bs[2][64 * 64];

    const int Kd   = DIMF;
    const int tid  = threadIdx.x;
    const int wave = tid >> 6;
    const int lane = tid & 63;
    const int row0 = blockIdx.y * 64;
    const int col0 = blockIdx.x * 64;
    const int wr = (wave >> 1) * 32;
    const int wc = (wave & 1) * 32;
    const int rl = lane >> 3;
    const int cl = lane & 7;

    f32x4 acc[2][2] = {};

#define STAGE(KT, AB, BB) do {                                                \
    _Pragma("unroll")                                                         \
    for (int h = 0; h < 2; ++h) {                                             \
        const int rbase = wave * 16 + h * 8;                                  \
        const int rA = rbase + rl;                                            \
        GLDS(A + (size_t)(row0 + rA) * Kd + (KT) * 64 + ((cl ^ (rA & 7)) * 8),\
             (AB) + rbase * 64);                                              \
        GLDS(B + (size_t)(col0 + rA) * Kd + (KT) * 64 + ((cl ^ (rA & 7)) * 8),\
             (BB) + rbase * 64);                                              \
    }                                                                         \
} while (0)

#define COMPUTE(AB, BB) do {                                                  \
    _Pragma("unroll")                                                         \
    for (int kh = 0; kh < 2; ++kh) {                                          \
        half8 a[2], b[2];                                                     \
        const int g = kh * 4 + (lane >> 4);                                   \
        _Pragma("unroll")                                                     \
        for (int i = 0; i < 2; ++i) {                                         \
            const int ra = wr + i * 16 + (lane & 15);                         \
            const int rb = wc + i * 16 + (lane & 15);                         \
            a[i] = *(const half8*)((AB) + ra * 64 + ((g ^ (ra & 7)) * 8));    \
            b[i] = *(const half8*)((BB) + rb * 64 + ((g ^ (rb & 7)) * 8));    \
        }                                                                     \
        _Pragma("unroll")                                                     \
        for (int i = 0; i < 2; ++i)                                           \
            _Pragma("unroll")                                                 \
            for (int j = 0; j < 2; ++j)                                       \
                acc[i][j] = __builtin_amdgcn_mfma_f32_16x16x32_f16(           \
                    a[i], b[j], acc[i][j], 0, 0, 0);                          \
    }                                                                         \
} while (0)

    STAGE(0, As[0], Bs[0]);
    __syncthreads();                       // drains vmcnt -> buf0 ready
    for (int kt = 0; kt < 16; kt += 2) {
        STAGE(kt + 1, As[1], Bs[1]);       // overlap with compute of buf0
        COMPUTE(As[0], Bs[0]);
        __syncthreads();                   // buf1 ready; all reads of buf0 done
        if (kt + 2 < 16) STAGE(kt + 2, As[0], Bs[0]);
        COMPUTE(As[1], Bs[1]);
        __syncthreads();                   // buf0 ready; reads of buf1 done
    }
#undef STAGE
#undef COMPUTE

    // C/D layout: col = lane&15, row = (lane>>4)*4 + reg
    if (MODE == 0) {
#pragma unroll
        for (int i = 0; i < 2; ++i) {
#pragma unroll
            for (int reg = 0; reg < 4; ++reg) {
                const int r  = row0 + wr + i * 16 + (lane >> 4) * 4 + reg;
                const int bt = r >> 8;
                const int s  = r & 255;
                const int hh = s >> 4;
                const int ww = s & 15;
#pragma unroll
                for (int j = 0; j < 2; ++j) {
                    const float v     = acc[i][j][reg];
                    const float other = __shfl_xor(v, 1);   // RoPE pair partner
                    const int n    = col0 + wc + j * 16 + (lane & 15);
                    const int sec  = n >> 10;       // 0=q,1=k,2=v
                    const int oi   = n & 1023;
                    const int head = oi >> 6;
                    const int d    = oi & 63;
                    if (sec == 2) {
                        vb[(((size_t)(bt * NH + head)) * DH + d) * SEQ + s] = (_Float16)v;
                    } else {
                        const int de  = d & ~1;
                        const int j2  = (de < 32) ? (de >> 1) : ((de - 32) >> 1);
                        const float pos = (de < 32) ? (-1.f + hh * (2.f / 15.f))
                                                    : (-1.f + ww * (2.f / 15.f));
                        const float f  = pos * (PI_F * (1.f + j2 * (127.f / 15.f)));
                        const float cf = __cosf(f), sf = __sinf(f);
                        const float res = (d & 1) ? (v * cf + other * sf)
                                                  : (v * cf - other * sf);
                        _Float16* dp = (sec == 0) ? qb : kb;
                        dp[(((size_t)(bt * NH + head)) * SEQ + s) * DH + d] = (_Float16)res;
                    }
                }
            }
        }
    } else {
#pragma unroll
        for (int i = 0; i < 2; ++i)
#pragma unroll
            for (int reg = 0; reg < 4; ++reg) {
                const int r = row0 + wr + i * 16 + (lane >> 4) * 4 + reg;
#pragma unroll
                for (int j = 0; j < 2; ++j) {
                    const int n = col0 + wc + j * 16 + (lane & 15);
                    out[(size_t)r * N + n] = acc[i][j][reg] + bias[n];
                }
            }
    }
}

// ---------------------------------------------------------------------------
// Register-resident dense-score top-k attention (round-6 verified).
// 512 blocks x 4 waves; LDS = 16KB score/prob matrix only.
// ---------------------------------------------------------------------------
__global__ __launch_bounds__(256)
void attn_reg16_kernel(const _Float16* __restrict__ qh, const _Float16* __restrict__ kh,
                       const _Float16* __restrict__ vt, const int* __restrict__ topk,
                       const float* __restrict__ ontk, _Float16* __restrict__ attnh)
{
    __shared__ __align__(16) float Ps[QT * 256];   // 16 KB

    const int tid  = threadIdx.x;
    const int w    = tid >> 6;
    const int lane = tid & 63;
    const int bid  = blockIdx.x;
    const int bt   = bid >> 8;
    const int head = (bid >> 4) & 15;
    const int s0   = (bid & 15) * QT;
    const int bh   = bt * NH + head;

    // Q a-frags / K b-frags first (phase-A critical path)
    half8 aq[2], bk[2][4];
#pragma unroll
    for (int kk = 0; kk < 2; ++kk) {
        const int c8 = (kk * 4 + (lane >> 4)) * 8;
        aq[kk] = *(const half8*)(qh + ((size_t)bh * SEQ + s0 + (lane & 15)) * DH + c8);
#pragma unroll
        for (int j = 0; j < 4; ++j)
            bk[kk][j] = *(const half8*)(kh + ((size_t)bh * SEQ + w * 64 + j * 16 + (lane & 15)) * DH + c8);
    }
    int ki0[4], ki1[4], ki2[4];
#pragma unroll
    for (int qq = 0; qq < 4; ++qq) {
        const int* idxp = topk + ((size_t)bh * SEQ + s0 + w * 4 + qq) * KTOP;
        ki0[qq] = idxp[lane];
        ki1[qq] = idxp[lane + 64];
        ki2[qq] = idxp[(lane < 16) ? (lane + 128) : lane];
    }
    half8 bv[8];
    {
        const _Float16* vrow = vt + ((size_t)bh * DH + w * 16 + (lane & 15)) * SEQ
                                  + (lane >> 4) * 8;
#pragma unroll
        for (int ks = 0; ks < 8; ++ks)
            bv[ks] = *(const half8*)(vrow + ks * 32);
    }
    float on[4];
#pragma unroll
    for (int reg = 0; reg < 4; ++reg) {
        const int row = (lane >> 4) * 4 + reg;
        on[reg] = ontk[((size_t)bh * SEQ + s0 + row) * DH + w * 16 + (lane & 15)];
    }

    // Phase A: S[16][256]
    f32x4 acc[4] = {};
#pragma unroll
    for (int kk = 0; kk < 2; ++kk)
#pragma unroll
        for (int j = 0; j < 4; ++j)
            acc[j] = __builtin_amdgcn_mfma_f32_16x16x32_f16(aq[kk], bk[kk][j], acc[j], 0, 0, 0);
#pragma unroll
    for (int j = 0; j < 4; ++j)
#pragma unroll
        for (int reg = 0; reg < 4; ++reg) {
            const int row = (lane >> 4) * 4 + reg;
            const int col = w * 64 + j * 16 + (lane & 15);
            Ps[row * 256 + (col ^ ((row & 7) << 2))] = acc[j][reg];
        }
    __syncthreads();

    // Phase B: softmax + prob scatter (atomicAdd sums duplicate indices)
#pragma unroll
    for (int qq = 0; qq < 4; ++qq) {
        const int q  = w * 4 + qq;
        const int sw = (q & 7) << 2;
        float* prow  = Ps + q * 256;
        const float sv0 = prow[ki0[qq] ^ sw] * 0.125f;
        const float sv1 = prow[ki1[qq] ^ sw] * 0.125f;
        const float sv2 = (lane < 16) ? prow[ki2[qq] ^ sw] * 0.125f : -1e30f;
        float m = fmaxf(fmaxf(sv0, sv1), sv2);
#pragma unroll
        for (int off = 32; off; off >>= 1) m = fmaxf(m, __shfl_xor(m, off));
        const float e0 = __expf(sv0 - m);
        const float e1 = __expf(sv1 - m);
        const float e2 = (lane < 16) ? __expf(sv2 - m) : 0.f;
        float z = e0 + e1 + e2;
#pragma unroll
        for (int off = 32; off; off >>= 1) z += __shfl_xor(z, off);
        const float inv = 1.f / z;
#pragma unroll
        for (int c2 = 0; c2 < 4; ++c2) prow[lane + c2 * 64] = 0.f;
        atomicAdd(&prow[ki0[qq] ^ sw], e0 * inv);
        atomicAdd(&prow[ki1[qq] ^ sw], e1 * inv);
        if (lane < 16) atomicAdd(&prow[ki2[qq] ^ sw], e2 * inv);
    }
    __syncthreads();

    // Phase C: out[16][64] = P.V ; wave w owns d-cols w*16..+15
    f32x4 oacc = {};
#pragma unroll
    for (int ks = 0; ks < 8; ++ks) {
        const int ra = lane & 15;
        const int b0 = ks * 32 + (lane >> 4) * 8;
        const int sw = (ra & 7) << 2;
        const float4 p0 = *(const float4*)(Ps + ra * 256 + (b0 ^ sw));
        const float4 p1 = *(const float4*)(Ps + ra * 256 + ((b0 + 4) ^ sw));
        half8 af;
        af[0] = (_Float16)p0.x; af[1] = (_Float16)p0.y;
        af[2] = (_Float16)p0.z; af[3] = (_Float16)p0.w;
        af[4] = (_Float16)p1.x; af[5] = (_Float16)p1.y;
        af[6] = (_Float16)p1.z; af[7] = (_Float16)p1.w;
        oacc = __builtin_amdgcn_mfma_f32_16x16x32_f16(af, bv[ks], oacc, 0, 0, 0);
    }
#pragma unroll
    for (int reg = 0; reg < 4; ++reg) {
        const int row = (lane >> 4) * 4 + reg;
        const int d   = w * 16 + (lane & 15);
        const int s   = s0 + row;
        attnh[((size_t)(bt * SEQ + s)) * DIMF + head * DH + d] = (_Float16)(oacc[reg] + on[reg]);
    }
}

// ---------------------------------------------------------------------------
extern "C" void kernel_launch(void* const* d_in, const int* in_sizes, int n_in,
                              void* d_out, int out_size, void* d_ws, size_t ws_size,
                              hipStream_t stream) {
    const float* x     = (const float*)d_in[0];
    const float* w_qkv = (const float*)d_in[1];
    const float* w_out = (const float*)d_in[2];
    const float* b_out = (const float*)d_in[3];
    const float* ontk  = (const float*)d_in[4];
    const int*   topk  = (const int*)d_in[5];
    float* out = (float*)d_out;

    const size_t QE = (size_t)BTN * NH * SEQ * DH;   // 524288

    _Float16* xh    = (_Float16*)d_ws;
    _Float16* wqh   = xh + 524288;
    _Float16* woh   = wqh + 3145728;
    _Float16* attnh = woh + 1048576;
    _Float16* qhb   = attnh + QE;
    _Float16* khb   = qhb + QE;
    _Float16* vtb   = khb + QE;

    // 1) fp32->fp16 inputs
    cvt3_kernel<<<(N0Q + N1Q + N2Q) / 256, 256, 0, stream>>>(x, w_qkv, w_out, xh, wqh, woh);

    // 2) qkv projection + RoPE -> fp16 q,k (bt,head,s,d); v^T (bt,head,d,s)
    gemm_dbuf_kernel<0><<<dim3(3072 / 64, 512 / 64), 256, 0, stream>>>(
        xh, wqh, 3072, qhb, khb, vtb, nullptr, nullptr);

    // 3) high-occupancy register-resident top-k attention (512 blocks)
    attn_reg16_kernel<<<BTN * NH * (SEQ / QT), 256, 0, stream>>>(
        qhb, khb, vtb, topk, ontk, attnh);

    // 4) output projection + bias
    gemm_dbuf_kernel<1><<<dim3(1024 / 64, 512 / 64), 256, 0, stream>>>(
        attnh, woh, 1024, nullptr, nullptr, nullptr, b_out, out);
}

// Round 11
// 46.440 us; speedup vs baseline: 1.2045x; 1.2045x over previous
//
#include <hip/hip_runtime.h>
#include <hip/hip_bf16.h>
#include <math.h>

// SpatialAxialAttention: B*T=2, H=W=16, dim=1024, HEADS=16, DIM_HEAD=64, K=144
#define BTN   2
#define NH    16
#define SEQ   256
#define DH    64
#define DIMF  1024
#define KTOP  144
#define QT    16
#define PI_F  3.14159265358979323846f

typedef _Float16 half8 __attribute__((ext_vector_type(8)));
typedef _Float16 half4v __attribute__((ext_vector_type(4)));
typedef float f32x4 __attribute__((ext_vector_type(4)));

#define GLDS(src, dst) __builtin_amdgcn_global_load_lds( \
        (const __attribute__((address_space(1))) void*)(src), \
        (__attribute__((address_space(3))) void*)(dst), 16, 0, 0)

// ---------------------------------------------------------------------------
// fp32 -> fp16 conversion for x, w_qkv, w_out
// ---------------------------------------------------------------------------
#define N0Q (524288 / 4)
#define N1Q (3145728 / 4)
#define N2Q (1048576 / 4)
__global__ __launch_bounds__(256)
void cvt3_kernel(const float* __restrict__ a, const float* __restrict__ b,
                 const float* __restrict__ c,
                 _Float16* __restrict__ da, _Float16* __restrict__ db,
                 _Float16* __restrict__ dc)
{
    int q = blockIdx.x * 256 + threadIdx.x;
    const float* s; _Float16* d; int off;
    if (q < N0Q)            { s = a; d = da; off = q; }
    else if (q < N0Q + N1Q) { s = b; d = db; off = q - N0Q; }
    else                    { s = c; d = dc; off = q - (N0Q + N1Q); }
    const float4 v = *(const float4*)(s + (size_t)off * 4);
    half4v h;
    h[0] = (_Float16)v.x; h[1] = (_Float16)v.y;
    h[2] = (_Float16)v.z; h[3] = (_Float16)v.w;
    *(half4v*)(d + (size_t)off * 4) = h;
}

// ---------------------------------------------------------------------------
// fp16 MFMA NT-GEMM, SMALL-TILE high-occupancy version: BM=32, BN=64, BK=64,
// 256 threads (4 waves; wave w owns output cols w*16..w*16+15, rows 0..31).
// 12 KB LDS. Grid: gemm0 768 blocks (3.0/CU balanced), gemm1 256 (1.0/CU).
// Inter-block TLP hides the per-K-tile staging drains (m114 overlap).
// global_load_lds staging with the verified 16B-chunk XOR swizzle.
// MODE 0: epilogue splits qkv, RoPE on q,k -> fp16 (bt,head,s,d);
//         v -> fp16 TRANSPOSED (bt,head,d,s). MODE 1: +bias fp32 store.
// ---------------------------------------------------------------------------
template <int MODE>
__global__ __launch_bounds__(256)
void gemm32_kernel(const _Float16* __restrict__ A, const _Float16* __restrict__ B,
                   int N,
                   _Float16* __restrict__ qb, _Float16* __restrict__ kb,
                   _Float16* __restrict__ vb,
                   const float* __restrict__ bias, float* __restrict__ out)
{
    __shared__ __align__(16) _Float16 As[32 * 64];   // 4 KB
    __shared__ __align__(16) _Float16 Bs[64 * 64];   // 8 KB

    const int Kd   = DIMF;
    const int tid  = threadIdx.x;
    const int wave = tid >> 6;
    const int lane = tid & 63;
    const int row0 = blockIdx.y * 32;
    const int col0 = blockIdx.x * 64;
    const int rl = lane >> 3;
    const int cl = lane & 7;

    f32x4 acc[2] = {};

    for (int kt = 0; kt < Kd; kt += 64) {
        __syncthreads();
        // A: 32 rows; wave w stages rows w*8..w*8+7 (1 GLDS)
        {
            const int rA = wave * 8 + rl;
            GLDS(A + (size_t)(row0 + rA) * Kd + kt + ((cl ^ (rA & 7)) * 8),
                 As + wave * 8 * 64);
        }
        // B: 64 rows; wave w stages rows w*16..w*16+15 (2 GLDS)
#pragma unroll
        for (int h = 0; h < 2; ++h) {
            const int rB = wave * 16 + h * 8 + rl;
            GLDS(B + (size_t)(col0 + rB) * Kd + kt + ((cl ^ (rB & 7)) * 8),
                 Bs + (wave * 16 + h * 8) * 64);
        }
        __syncthreads();

#pragma unroll
        for (int kh = 0; kh < 2; ++kh) {
            const int g = kh * 4 + (lane >> 4);
            half8 a[2], b;
#pragma unroll
            for (int i = 0; i < 2; ++i) {
                const int ra = i * 16 + (lane & 15);
                a[i] = *(const half8*)(As + ra * 64 + ((g ^ (ra & 7)) * 8));
            }
            const int rb = wave * 16 + (lane & 15);
            b = *(const half8*)(Bs + rb * 64 + ((g ^ (rb & 7)) * 8));
#pragma unroll
            for (int i = 0; i < 2; ++i)
                acc[i] = __builtin_amdgcn_mfma_f32_16x16x32_f16(a[i], b, acc[i], 0, 0, 0);
        }
    }

    // C/D layout: col = lane&15, row = (lane>>4)*4 + reg
    if (MODE == 0) {
#pragma unroll
        for (int i = 0; i < 2; ++i) {
#pragma unroll
            for (int reg = 0; reg < 4; ++reg) {
                const int r  = row0 + i * 16 + (lane >> 4) * 4 + reg;
                const int bt = r >> 8;
                const int s  = r & 255;
                const int hh = s >> 4;
                const int ww = s & 15;
                const float v     = acc[i][reg];
                const float other = __shfl_xor(v, 1);   // RoPE pair partner
                const int n    = col0 + wave * 16 + (lane & 15);
                const int sec  = n >> 10;       // 0=q,1=k,2=v
                const int oi   = n & 1023;
                const int head = oi >> 6;
                const int d    = oi & 63;
                if (sec == 2) {
                    vb[(((size_t)(bt * NH + head)) * DH + d) * SEQ + s] = (_Float16)v;
                } else {
                    const int de  = d & ~1;
                    const int j2  = (de < 32) ? (de >> 1) : ((de - 32) >> 1);
                    const float pos = (de < 32) ? (-1.f + hh * (2.f / 15.f))
                                                : (-1.f + ww * (2.f / 15.f));
                    const float f  = pos * (PI_F * (1.f + j2 * (127.f / 15.f)));
                    const float cf = __cosf(f), sf = __sinf(f);
                    const float res = (d & 1) ? (v * cf + other * sf)
                                              : (v * cf - other * sf);
                    _Float16* dp = (sec == 0) ? qb : kb;
                    dp[(((size_t)(bt * NH + head)) * SEQ + s) * DH + d] = (_Float16)res;
                }
            }
        }
    } else {
#pragma unroll
        for (int i = 0; i < 2; ++i)
#pragma unroll
            for (int reg = 0; reg < 4; ++reg) {
                const int r = row0 + i * 16 + (lane >> 4) * 4 + reg;
                const int n = col0 + wave * 16 + (lane & 15);
                out[(size_t)r * N + n] = acc[i][reg] + bias[n];
            }
    }
}

// ---------------------------------------------------------------------------
// Register-resident dense-score top-k attention (round-6 verified).
// 512 blocks x 4 waves; LDS = 16KB score/prob matrix only.
// ---------------------------------------------------------------------------
__global__ __launch_bounds__(256)
void attn_reg16_kernel(const _Float16* __restrict__ qh, const _Float16* __restrict__ kh,
                       const _Float16* __restrict__ vt, const int* __restrict__ topk,
                       const float* __restrict__ ontk, _Float16* __restrict__ attnh)
{
    __shared__ __align__(16) float Ps[QT * 256];   // 16 KB

    const int tid  = threadIdx.x;
    const int w    = tid >> 6;
    const int lane = tid & 63;
    const int bid  = blockIdx.x;
    const int bt   = bid >> 8;
    const int head = (bid >> 4) & 15;
    const int s0   = (bid & 15) * QT;
    const int bh   = bt * NH + head;

    // Q a-frags / K b-frags first (phase-A critical path)
    half8 aq[2], bk[2][4];
#pragma unroll
    for (int kk = 0; kk < 2; ++kk) {
        const int c8 = (kk * 4 + (lane >> 4)) * 8;
        aq[kk] = *(const half8*)(qh + ((size_t)bh * SEQ + s0 + (lane & 15)) * DH + c8);
#pragma unroll
        for (int j = 0; j < 4; ++j)
            bk[kk][j] = *(const half8*)(kh + ((size_t)bh * SEQ + w * 64 + j * 16 + (lane & 15)) * DH + c8);
    }
    int ki0[4], ki1[4], ki2[4];
#pragma unroll
    for (int qq = 0; qq < 4; ++qq) {
        const int* idxp = topk + ((size_t)bh * SEQ + s0 + w * 4 + qq) * KTOP;
        ki0[qq] = idxp[lane];
        ki1[qq] = idxp[lane + 64];
        ki2[qq] = idxp[(lane < 16) ? (lane + 128) : lane];
    }
    half8 bv[8];
    {
        const _Float16* vrow = vt + ((size_t)bh * DH + w * 16 + (lane & 15)) * SEQ
                                  + (lane >> 4) * 8;
#pragma unroll
        for (int ks = 0; ks < 8; ++ks)
            bv[ks] = *(const half8*)(vrow + ks * 32);
    }
    float on[4];
#pragma unroll
    for (int reg = 0; reg < 4; ++reg) {
        const int row = (lane >> 4) * 4 + reg;
        on[reg] = ontk[((size_t)bh * SEQ + s0 + row) * DH + w * 16 + (lane & 15)];
    }

    // Phase A: S[16][256]
    f32x4 acc[4] = {};
#pragma unroll
    for (int kk = 0; kk < 2; ++kk)
#pragma unroll
        for (int j = 0; j < 4; ++j)
            acc[j] = __builtin_amdgcn_mfma_f32_16x16x32_f16(aq[kk], bk[kk][j], acc[j], 0, 0, 0);
#pragma unroll
    for (int j = 0; j < 4; ++j)
#pragma unroll
        for (int reg = 0; reg < 4; ++reg) {
            const int row = (lane >> 4) * 4 + reg;
            const int col = w * 64 + j * 16 + (lane & 15);
            Ps[row * 256 + (col ^ ((row & 7) << 2))] = acc[j][reg];
        }
    __syncthreads();

    // Phase B: softmax + prob scatter (atomicAdd sums duplicate indices)
#pragma unroll
    for (int qq = 0; qq < 4; ++qq) {
        const int q  = w * 4 + qq;
        const int sw = (q & 7) << 2;
        float* prow  = Ps + q * 256;
        const float sv0 = prow[ki0[qq] ^ sw] * 0.125f;
        const float sv1 = prow[ki1[qq] ^ sw] * 0.125f;
        const float sv2 = (lane < 16) ? prow[ki2[qq] ^ sw] * 0.125f : -1e30f;
        float m = fmaxf(fmaxf(sv0, sv1), sv2);
#pragma unroll
        for (int off = 32; off; off >>= 1) m = fmaxf(m, __shfl_xor(m, off));
        const float e0 = __expf(sv0 - m);
        const float e1 = __expf(sv1 - m);
        const float e2 = (lane < 16) ? __expf(sv2 - m) : 0.f;
        float z = e0 + e1 + e2;
#pragma unroll
        for (int off = 32; off; off >>= 1) z += __shfl_xor(z, off);
        const float inv = 1.f / z;
#pragma unroll
        for (int c2 = 0; c2 < 4; ++c2) prow[lane + c2 * 64] = 0.f;
        atomicAdd(&prow[ki0[qq] ^ sw], e0 * inv);
        atomicAdd(&prow[ki1[qq] ^ sw], e1 * inv);
        if (lane < 16) atomicAdd(&prow[ki2[qq] ^ sw], e2 * inv);
    }
    __syncthreads();

    // Phase C: out[16][64] = P.V ; wave w owns d-cols w*16..+15
    f32x4 oacc = {};
#pragma unroll
    for (int ks = 0; ks < 8; ++ks) {
        const int ra = lane & 15;
        const int b0 = ks * 32 + (lane >> 4) * 8;
        const int sw = (ra & 7) << 2;
        const float4 p0 = *(const float4*)(Ps + ra * 256 + (b0 ^ sw));
        const float4 p1 = *(const float4*)(Ps + ra * 256 + ((b0 + 4) ^ sw));
        half8 af;
        af[0] = (_Float16)p0.x; af[1] = (_Float16)p0.y;
        af[2] = (_Float16)p0.z; af[3] = (_Float16)p0.w;
        af[4] = (_Float16)p1.x; af[5] = (_Float16)p1.y;
        af[6] = (_Float16)p1.z; af[7] = (_Float16)p1.w;
        oacc = __builtin_amdgcn_mfma_f32_16x16x32_f16(af, bv[ks], oacc, 0, 0, 0);
    }
#pragma unroll
    for (int reg = 0; reg < 4; ++reg) {
        const int row = (lane >> 4) * 4 + reg;
        const int d   = w * 16 + (lane & 15);
        const int s   = s0 + row;
        attnh[((size_t)(bt * SEQ + s)) * DIMF + head * DH + d] = (_Float16)(oacc[reg] + on[reg]);
    }
}

// ---------------------------------------------------------------------------
extern "C" void kernel_launch(void* const* d_in, const int* in_sizes, int n_in,
                              void* d_out, int out_size, void* d_ws, size_t ws_size,
                              hipStream_t stream) {
    const float* x     = (const float*)d_in[0];
    const float* w_qkv = (const float*)d_in[1];
    const float* w_out = (const float*)d_in[2];
    const float* b_out = (const float*)d_in[3];
    const float* ontk  = (const float*)d_in[4];
    const int*   topk  = (const int*)d_in[5];
    float* out = (float*)d_out;

    const size_t QE = (size_t)BTN * NH * SEQ * DH;   // 524288

    _Float16* xh    = (_Float16*)d_ws;
    _Float16* wqh   = xh + 524288;
    _Float16* woh   = wqh + 3145728;
    _Float16* attnh = woh + 1048576;
    _Float16* qhb   = attnh + QE;
    _Float16* khb   = qhb + QE;
    _Float16* vtb   = khb + QE;

    // 1) fp32->fp16 inputs
    cvt3_kernel<<<(N0Q + N1Q + N2Q) / 256, 256, 0, stream>>>(x, w_qkv, w_out, xh, wqh, woh);

    // 2) qkv projection + RoPE (768 blocks = 3.0/CU balanced)
    gemm32_kernel<0><<<dim3(3072 / 64, 512 / 32), 256, 0, stream>>>(
        xh, wqh, 3072, qhb, khb, vtb, nullptr, nullptr);

    // 3) high-occupancy register-resident top-k attention (512 blocks)
    attn_reg16_kernel<<<BTN * NH * (SEQ / QT), 256, 0, stream>>>(
        qhb, khb, vtb, topk, ontk, attnh);

    // 4) output projection + bias (256 blocks = 1.0/CU, all CUs active)
    gemm32_kernel<1><<<dim3(1024 / 64, 512 / 32), 256, 0, stream>>>(
        attnh, woh, 1024, nullptr, nullptr, nullptr, b_out, out);
}

// Round 12
// 41.470 us; speedup vs baseline: 1.3489x; 1.1199x over previous
//
#include <hip/hip_runtime.h>
#include <hip/hip_bf16.h>
#include <math.h>

// SpatialAxialAttention: B*T=2, H=W=16, dim=1024, HEADS=16, DIM_HEAD=64, K=144
#define BTN   2
#define NH    16
#define SEQ   256
#define DH    64
#define DIMF  1024
#define KTOP  144
#define QT    16
#define PI_F  3.14159265358979323846f

typedef _Float16 half8 __attribute__((ext_vector_type(8)));
typedef _Float16 half4v __attribute__((ext_vector_type(4)));
typedef float f32x4 __attribute__((ext_vector_type(4)));

#define GLDS(src, dst) __builtin_amdgcn_global_load_lds( \
        (const __attribute__((address_space(1))) void*)(src), \
        (__attribute__((address_space(3))) void*)(dst), 16, 0, 0)

// ---------------------------------------------------------------------------
// fp32 -> fp16 conversion for x, w_qkv, w_out
// ---------------------------------------------------------------------------
#define N0Q (524288 / 4)
#define N1Q (3145728 / 4)
#define N2Q (1048576 / 4)
__global__ __launch_bounds__(256)
void cvt3_kernel(const float* __restrict__ a, const float* __restrict__ b,
                 const float* __restrict__ c,
                 _Float16* __restrict__ da, _Float16* __restrict__ db,
                 _Float16* __restrict__ dc)
{
    int q = blockIdx.x * 256 + threadIdx.x;
    const float* s; _Float16* d; int off;
    if (q < N0Q)            { s = a; d = da; off = q; }
    else if (q < N0Q + N1Q) { s = b; d = db; off = q - N0Q; }
    else                    { s = c; d = dc; off = q - (N0Q + N1Q); }
    const float4 v = *(const float4*)(s + (size_t)off * 4);
    half4v h;
    h[0] = (_Float16)v.x; h[1] = (_Float16)v.y;
    h[2] = (_Float16)v.z; h[3] = (_Float16)v.w;
    *(half4v*)(d + (size_t)off * 4) = h;
}

// ---------------------------------------------------------------------------
// fp16 MFMA NT-GEMM, BK=128 (8 K-iterations -> half the barrier drains of
// BK=64), small tiles for grid balance:
//   MODE 0: BM=32 x BN=64, grid (48,16)=768 blocks (3.0/CU). Wave w owns
//           output cols w*16..+15, rows 0..31 (2 frags).
//   MODE 1: BM=32 x BN=32, grid (32,16)=512 blocks (2.0/CU). Waves in 2x2:
//           wave w owns rows (w>>1)*16, cols (w&1)*16 (1 frag).
// 16-chunk-per-row XOR swizzle (chunk ^= row&15): frag reads land 2 rows/bank
// pair = free (m136). global_load_lds linear dest + pre-swizzled source.
// MODE 0 epilogue: split qkv -> RoPE q,k -> fp16 (bt,head,s,d); v -> fp16
// transposed (bt,head,d,s). MODE 1: +bias fp32 store.
// ---------------------------------------------------------------------------
template <int MODE>
__global__ __launch_bounds__(256)
void gemm_k128_kernel(const _Float16* __restrict__ A, const _Float16* __restrict__ B,
                      int N,
                      _Float16* __restrict__ qb, _Float16* __restrict__ kb,
                      _Float16* __restrict__ vb,
                      const float* __restrict__ bias, float* __restrict__ out)
{
    constexpr int BN = (MODE == 0) ? 64 : 32;
    __shared__ __align__(16) _Float16 As[32 * 128];    // 8 KB
    __shared__ __align__(16) _Float16 Bs[BN * 128];    // 16/8 KB

    const int Kd   = DIMF;
    const int tid  = threadIdx.x;
    const int wave = tid >> 6;
    const int lane = tid & 63;
    const int row0 = blockIdx.y * 32;
    const int col0 = blockIdx.x * BN;
    const int rl4  = lane >> 4;     // row within 4-row staging group
    const int cl16 = lane & 15;     // 16B chunk within 256B row

    f32x4 acc[2] = {};

    for (int kt = 0; kt < 8; ++kt) {
        __syncthreads();
        // A: 32 rows x 128; wave w stages rows w*8..w*8+7 (2 GLDS)
#pragma unroll
        for (int h = 0; h < 2; ++h) {
            const int rA = wave * 8 + h * 4 + rl4;
            GLDS(A + (size_t)(row0 + rA) * Kd + kt * 128 + ((cl16 ^ (rA & 15)) * 8),
                 As + (wave * 8 + h * 4) * 128);
        }
        // B: BN rows x 128
        if (MODE == 0) {
#pragma unroll
            for (int h = 0; h < 4; ++h) {
                const int rB = wave * 16 + h * 4 + rl4;
                GLDS(B + (size_t)(col0 + rB) * Kd + kt * 128 + ((cl16 ^ (rB & 15)) * 8),
                     Bs + (wave * 16 + h * 4) * 128);
            }
        } else {
#pragma unroll
            for (int h = 0; h < 2; ++h) {
                const int rB = wave * 8 + h * 4 + rl4;
                GLDS(B + (size_t)(col0 + rB) * Kd + kt * 128 + ((cl16 ^ (rB & 15)) * 8),
                     Bs + (wave * 8 + h * 4) * 128);
            }
        }
        __syncthreads();

#pragma unroll
        for (int kh = 0; kh < 4; ++kh) {
            const int g = kh * 4 + (lane >> 4);
            if (MODE == 0) {
                const int rb = wave * 16 + (lane & 15);
                const half8 b = *(const half8*)(Bs + rb * 128 + ((g ^ (rb & 15)) * 8));
#pragma unroll
                for (int i = 0; i < 2; ++i) {
                    const int ra = i * 16 + (lane & 15);
                    const half8 a = *(const half8*)(As + ra * 128 + ((g ^ (ra & 15)) * 8));
                    acc[i] = __builtin_amdgcn_mfma_f32_16x16x32_f16(a, b, acc[i], 0, 0, 0);
                }
            } else {
                const int ra = (wave >> 1) * 16 + (lane & 15);
                const int rb = (wave & 1) * 16 + (lane & 15);
                const half8 a = *(const half8*)(As + ra * 128 + ((g ^ (ra & 15)) * 8));
                const half8 b = *(const half8*)(Bs + rb * 128 + ((g ^ (rb & 15)) * 8));
                acc[0] = __builtin_amdgcn_mfma_f32_16x16x32_f16(a, b, acc[0], 0, 0, 0);
            }
        }
    }

    // C/D layout: col = lane&15, row = (lane>>4)*4 + reg
    if (MODE == 0) {
#pragma unroll
        for (int i = 0; i < 2; ++i) {
#pragma unroll
            for (int reg = 0; reg < 4; ++reg) {
                const int r  = row0 + i * 16 + (lane >> 4) * 4 + reg;
                const int bt = r >> 8;
                const int s  = r & 255;
                const int hh = s >> 4;
                const int ww = s & 15;
                const float v     = acc[i][reg];
                const float other = __shfl_xor(v, 1);   // RoPE pair partner
                const int n    = col0 + wave * 16 + (lane & 15);
                const int sec  = n >> 10;       // 0=q,1=k,2=v
                const int oi   = n & 1023;
                const int head = oi >> 6;
                const int d    = oi & 63;
                if (sec == 2) {
                    vb[(((size_t)(bt * NH + head)) * DH + d) * SEQ + s] = (_Float16)v;
                } else {
                    const int de  = d & ~1;
                    const int j2  = (de < 32) ? (de >> 1) : ((de - 32) >> 1);
                    const float pos = (de < 32) ? (-1.f + hh * (2.f / 15.f))
                                                : (-1.f + ww * (2.f / 15.f));
                    const float f  = pos * (PI_F * (1.f + j2 * (127.f / 15.f)));
                    const float cf = __cosf(f), sf = __sinf(f);
                    const float res = (d & 1) ? (v * cf + other * sf)
                                              : (v * cf - other * sf);
                    _Float16* dp = (sec == 0) ? qb : kb;
                    dp[(((size_t)(bt * NH + head)) * SEQ + s) * DH + d] = (_Float16)res;
                }
            }
        }
    } else {
#pragma unroll
        for (int reg = 0; reg < 4; ++reg) {
            const int r = row0 + (wave >> 1) * 16 + (lane >> 4) * 4 + reg;
            const int n = col0 + (wave & 1) * 16 + (lane & 15);
            out[(size_t)r * N + n] = acc[0][reg] + bias[n];
        }
    }
}

// ---------------------------------------------------------------------------
// Register-resident dense-score top-k attention (round-6 verified).
// 512 blocks x 4 waves; LDS = 16KB score/prob matrix only.
// ---------------------------------------------------------------------------
__global__ __launch_bounds__(256)
void attn_reg16_kernel(const _Float16* __restrict__ qh, const _Float16* __restrict__ kh,
                       const _Float16* __restrict__ vt, const int* __restrict__ topk,
                       const float* __restrict__ ontk, _Float16* __restrict__ attnh)
{
    __shared__ __align__(16) float Ps[QT * 256];   // 16 KB

    const int tid  = threadIdx.x;
    const int w    = tid >> 6;
    const int lane = tid & 63;
    const int bid  = blockIdx.x;
    const int bt   = bid >> 8;
    const int head = (bid >> 4) & 15;
    const int s0   = (bid & 15) * QT;
    const int bh   = bt * NH + head;

    // Q a-frags / K b-frags first (phase-A critical path)
    half8 aq[2], bk[2][4];
#pragma unroll
    for (int kk = 0; kk < 2; ++kk) {
        const int c8 = (kk * 4 + (lane >> 4)) * 8;
        aq[kk] = *(const half8*)(qh + ((size_t)bh * SEQ + s0 + (lane & 15)) * DH + c8);
#pragma unroll
        for (int j = 0; j < 4; ++j)
            bk[kk][j] = *(const half8*)(kh + ((size_t)bh * SEQ + w * 64 + j * 16 + (lane & 15)) * DH + c8);
    }
    int ki0[4], ki1[4], ki2[4];
#pragma unroll
    for (int qq = 0; qq < 4; ++qq) {
        const int* idxp = topk + ((size_t)bh * SEQ + s0 + w * 4 + qq) * KTOP;
        ki0[qq] = idxp[lane];
        ki1[qq] = idxp[lane + 64];
        ki2[qq] = idxp[(lane < 16) ? (lane + 128) : lane];
    }
    half8 bv[8];
    {
        const _Float16* vrow = vt + ((size_t)bh * DH + w * 16 + (lane & 15)) * SEQ
                                  + (lane >> 4) * 8;
#pragma unroll
        for (int ks = 0; ks < 8; ++ks)
            bv[ks] = *(const half8*)(vrow + ks * 32);
    }
    float on[4];
#pragma unroll
    for (int reg = 0; reg < 4; ++reg) {
        const int row = (lane >> 4) * 4 + reg;
        on[reg] = ontk[((size_t)bh * SEQ + s0 + row) * DH + w * 16 + (lane & 15)];
    }

    // Phase A: S[16][256]
    f32x4 acc[4] = {};
#pragma unroll
    for (int kk = 0; kk < 2; ++kk)
#pragma unroll
        for (int j = 0; j < 4; ++j)
            acc[j] = __builtin_amdgcn_mfma_f32_16x16x32_f16(aq[kk], bk[kk][j], acc[j], 0, 0, 0);
#pragma unroll
    for (int j = 0; j < 4; ++j)
#pragma unroll
        for (int reg = 0; reg < 4; ++reg) {
            const int row = (lane >> 4) * 4 + reg;
            const int col = w * 64 + j * 16 + (lane & 15);
            Ps[row * 256 + (col ^ ((row & 7) << 2))] = acc[j][reg];
        }
    __syncthreads();

    // Phase B: softmax + prob scatter (atomicAdd sums duplicate indices)
#pragma unroll
    for (int qq = 0; qq < 4; ++qq) {
        const int q  = w * 4 + qq;
        const int sw = (q & 7) << 2;
        float* prow  = Ps + q * 256;
        const float sv0 = prow[ki0[qq] ^ sw] * 0.125f;
        const float sv1 = prow[ki1[qq] ^ sw] * 0.125f;
        const float sv2 = (lane < 16) ? prow[ki2[qq] ^ sw] * 0.125f : -1e30f;
        float m = fmaxf(fmaxf(sv0, sv1), sv2);
#pragma unroll
        for (int off = 32; off; off >>= 1) m = fmaxf(m, __shfl_xor(m, off));
        const float e0 = __expf(sv0 - m);
        const float e1 = __expf(sv1 - m);
        const float e2 = (lane < 16) ? __expf(sv2 - m) : 0.f;
        float z = e0 + e1 + e2;
#pragma unroll
        for (int off = 32; off; off >>= 1) z += __shfl_xor(z, off);
        const float inv = 1.f / z;
#pragma unroll
        for (int c2 = 0; c2 < 4; ++c2) prow[lane + c2 * 64] = 0.f;
        atomicAdd(&prow[ki0[qq] ^ sw], e0 * inv);
        atomicAdd(&prow[ki1[qq] ^ sw], e1 * inv);
        if (lane < 16) atomicAdd(&prow[ki2[qq] ^ sw], e2 * inv);
    }
    __syncthreads();

    // Phase C: out[16][64] = P.V ; wave w owns d-cols w*16..+15
    f32x4 oacc = {};
#pragma unroll
    for (int ks = 0; ks < 8; ++ks) {
        const int ra = lane & 15;
        const int b0 = ks * 32 + (lane >> 4) * 8;
        const int sw = (ra & 7) << 2;
        const float4 p0 = *(const float4*)(Ps + ra * 256 + (b0 ^ sw));
        const float4 p1 = *(const float4*)(Ps + ra * 256 + ((b0 + 4) ^ sw));
        half8 af;
        af[0] = (_Float16)p0.x; af[1] = (_Float16)p0.y;
        af[2] = (_Float16)p0.z; af[3] = (_Float16)p0.w;
        af[4] = (_Float16)p1.x; af[5] = (_Float16)p1.y;
        af[6] = (_Float16)p1.z; af[7] = (_Float16)p1.w;
        oacc = __builtin_amdgcn_mfma_f32_16x16x32_f16(af, bv[ks], oacc, 0, 0, 0);
    }
#pragma unroll
    for (int reg = 0; reg < 4; ++reg) {
        const int row = (lane >> 4) * 4 + reg;
        const int d   = w * 16 + (lane & 15);
        const int s   = s0 + row;
        attnh[((size_t)(bt * SEQ + s)) * DIMF + head * DH + d] = (_Float16)(oacc[reg] + on[reg]);
    }
}

// ---------------------------------------------------------------------------
extern "C" void kernel_launch(void* const* d_in, const int* in_sizes, int n_in,
                              void* d_out, int out_size, void* d_ws, size_t ws_size,
                              hipStream_t stream) {
    const float* x     = (const float*)d_in[0];
    const float* w_qkv = (const float*)d_in[1];
    const float* w_out = (const float*)d_in[2];
    const float* b_out = (const float*)d_in[3];
    const float* ontk  = (const float*)d_in[4];
    const int*   topk  = (const int*)d_in[5];
    float* out = (float*)d_out;

    const size_t QE = (size_t)BTN * NH * SEQ * DH;   // 524288

    _Float16* xh    = (_Float16*)d_ws;
    _Float16* wqh   = xh + 524288;
    _Float16* woh   = wqh + 3145728;
    _Float16* attnh = woh + 1048576;
    _Float16* qhb   = attnh + QE;
    _Float16* khb   = qhb + QE;
    _Float16* vtb   = khb + QE;

    // 1) fp32->fp16 inputs
    cvt3_kernel<<<(N0Q + N1Q + N2Q) / 256, 256, 0, stream>>>(x, w_qkv, w_out, xh, wqh, woh);

    // 2) qkv projection + RoPE (768 blocks = 3.0/CU, BK=128)
    gemm_k128_kernel<0><<<dim3(3072 / 64, 512 / 32), 256, 0, stream>>>(
        xh, wqh, 3072, qhb, khb, vtb, nullptr, nullptr);

    // 3) high-occupancy register-resident top-k attention (512 blocks)
    attn_reg16_kernel<<<BTN * NH * (SEQ / QT), 256, 0, stream>>>(
        qhb, khb, vtb, topk, ontk, attnh);

    // 4) output projection + bias (512 blocks = 2.0/CU, BK=128)
    gemm_k128_kernel<1><<<dim3(1024 / 32, 512 / 32), 256, 0, stream>>>(
        attnh, woh, 1024, nullptr, nullptr, nullptr, b_out, out);
}

// Round 13
// 41.468 us; speedup vs baseline: 1.3490x; 1.0000x over previous
//
#include <hip/hip_runtime.h>
#include <hip/hip_bf16.h>
#include <math.h>

// SpatialAxialAttention: B*T=2, H=W=16, dim=1024, HEADS=16, DIM_HEAD=64, K=144
#define BTN   2
#define NH    16
#define SEQ   256
#define DH    64
#define DIMF  1024
#define KTOP  144
#define QT    16
#define PI_F  3.14159265358979323846f

typedef _Float16 half8 __attribute__((ext_vector_type(8)));
typedef _Float16 half4v __attribute__((ext_vector_type(4)));
typedef float f32x4 __attribute__((ext_vector_type(4)));

#define GLDS(src, dst) __builtin_amdgcn_global_load_lds( \
        (const __attribute__((address_space(1))) void*)(src), \
        (__attribute__((address_space(3))) void*)(dst), 16, 0, 0)

// ---------------------------------------------------------------------------
// fp32 -> fp16 conversion for x, w_qkv, w_out
// ---------------------------------------------------------------------------
#define N0Q (524288 / 4)
#define N1Q (3145728 / 4)
#define N2Q (1048576 / 4)
__global__ __launch_bounds__(256)
void cvt3_kernel(const float* __restrict__ a, const float* __restrict__ b,
                 const float* __restrict__ c,
                 _Float16* __restrict__ da, _Float16* __restrict__ db,
                 _Float16* __restrict__ dc)
{
    int q = blockIdx.x * 256 + threadIdx.x;
    const float* s; _Float16* d; int off;
    if (q < N0Q)            { s = a; d = da; off = q; }
    else if (q < N0Q + N1Q) { s = b; d = db; off = q - N0Q; }
    else                    { s = c; d = dc; off = q - (N0Q + N1Q); }
    const float4 v = *(const float4*)(s + (size_t)off * 4);
    half4v h;
    h[0] = (_Float16)v.x; h[1] = (_Float16)v.y;
    h[2] = (_Float16)v.z; h[3] = (_Float16)v.w;
    *(half4v*)(d + (size_t)off * 4) = h;
}

// ---------------------------------------------------------------------------
// fp16 MFMA NT-GEMM, BK=256 (4 K-iterations -> half the barrier drains of
// BK=128), small tiles for grid balance:
//   MODE 0: BM=32 x BN=64, grid (48,16)=768 blocks (3.0/CU, 48KB LDS).
//           Wave w owns output cols w*16..+15, rows 0..31 (2 frags).
//   MODE 1: BM=32 x BN=32, grid (32,16)=512 blocks (2.0/CU, 32KB LDS).
//           Wave w owns rows (w>>1)*16, cols (w&1)*16 (1 frag).
// Rows are 512B = 32x16B chunks; XOR swizzle chunk ^= row&15 (bijective,
// frag reads 2-way per bank group = free, m136). global_load_lds linear
// dest (each instr = 2 rows) + pre-swizzled global source.
// MODE 0 epilogue: split qkv -> RoPE q,k -> fp16 (bt,head,s,d); v -> fp16
// transposed (bt,head,d,s). MODE 1: +bias fp32 store.
// ---------------------------------------------------------------------------
template <int MODE>
__global__ __launch_bounds__(256)
void gemm_k256_kernel(const _Float16* __restrict__ A, const _Float16* __restrict__ B,
                      int N,
                      _Float16* __restrict__ qb, _Float16* __restrict__ kb,
                      _Float16* __restrict__ vb,
                      const float* __restrict__ bias, float* __restrict__ out)
{
    constexpr int BN = (MODE == 0) ? 64 : 32;
    __shared__ __align__(16) _Float16 As[32 * 256];    // 16 KB
    __shared__ __align__(16) _Float16 Bs[BN * 256];    // 32/16 KB

    const int Kd   = DIMF;
    const int tid  = threadIdx.x;
    const int wave = tid >> 6;
    const int lane = tid & 63;
    const int row0 = blockIdx.y * 32;
    const int col0 = blockIdx.x * BN;
    const int rl2  = lane >> 5;     // row within 2-row staging group
    const int cl32 = lane & 31;     // 16B chunk within 512B row

    f32x4 acc[2] = {};

    for (int kt = 0; kt < 4; ++kt) {
        __syncthreads();
        // A: 32 rows x 256; wave w stages rows w*8..w*8+7 (4 GLDS, 2 rows each)
#pragma unroll
        for (int h = 0; h < 4; ++h) {
            const int rA = wave * 8 + h * 2 + rl2;
            GLDS(A + (size_t)(row0 + rA) * Kd + kt * 256 + ((cl32 ^ (rA & 15)) * 8),
                 As + (wave * 8 + h * 2) * 256);
        }
        // B: BN rows x 256; wave w stages BN/4 rows
#pragma unroll
        for (int h = 0; h < BN / 8; ++h) {
            const int rB = wave * (BN / 4) + h * 2 + rl2;
            GLDS(B + (size_t)(col0 + rB) * Kd + kt * 256 + ((cl32 ^ (rB & 15)) * 8),
                 Bs + (wave * (BN / 4) + h * 2) * 256);
        }
        __syncthreads();

#pragma unroll
        for (int kh = 0; kh < 8; ++kh) {
            const int g = kh * 4 + (lane >> 4);
            if (MODE == 0) {
                const int rb = wave * 16 + (lane & 15);
                const half8 b = *(const half8*)(Bs + rb * 256 + ((g ^ (rb & 15)) * 8));
#pragma unroll
                for (int i = 0; i < 2; ++i) {
                    const int ra = i * 16 + (lane & 15);
                    const half8 a = *(const half8*)(As + ra * 256 + ((g ^ (ra & 15)) * 8));
                    acc[i] = __builtin_amdgcn_mfma_f32_16x16x32_f16(a, b, acc[i], 0, 0, 0);
                }
            } else {
                const int ra = (wave >> 1) * 16 + (lane & 15);
                const int rb = (wave & 1) * 16 + (lane & 15);
                const half8 a = *(const half8*)(As + ra * 256 + ((g ^ (ra & 15)) * 8));
                const half8 b = *(const half8*)(Bs + rb * 256 + ((g ^ (rb & 15)) * 8));
                acc[0] = __builtin_amdgcn_mfma_f32_16x16x32_f16(a, b, acc[0], 0, 0, 0);
            }
        }
    }

    // C/D layout: col = lane&15, row = (lane>>4)*4 + reg
    if (MODE == 0) {
#pragma unroll
        for (int i = 0; i < 2; ++i) {
#pragma unroll
            for (int reg = 0; reg < 4; ++reg) {
                const int r  = row0 + i * 16 + (lane >> 4) * 4 + reg;
                const int bt = r >> 8;
                const int s  = r & 255;
                const int hh = s >> 4;
                const int ww = s & 15;
                const float v     = acc[i][reg];
                const float other = __shfl_xor(v, 1);   // RoPE pair partner
                const int n    = col0 + wave * 16 + (lane & 15);
                const int sec  = n >> 10;       // 0=q,1=k,2=v
                const int oi   = n & 1023;
                const int head = oi >> 6;
                const int d    = oi & 63;
                if (sec == 2) {
                    vb[(((size_t)(bt * NH + head)) * DH + d) * SEQ + s] = (_Float16)v;
                } else {
                    const int de  = d & ~1;
                    const int j2  = (de < 32) ? (de >> 1) : ((de - 32) >> 1);
                    const float pos = (de < 32) ? (-1.f + hh * (2.f / 15.f))
                                                : (-1.f + ww * (2.f / 15.f));
                    const float f  = pos * (PI_F * (1.f + j2 * (127.f / 15.f)));
                    const float cf = __cosf(f), sf = __sinf(f);
                    const float res = (d & 1) ? (v * cf + other * sf)
                                              : (v * cf - other * sf);
                    _Float16* dp = (sec == 0) ? qb : kb;
                    dp[(((size_t)(bt * NH + head)) * SEQ + s) * DH + d] = (_Float16)res;
                }
            }
        }
    } else {
#pragma unroll
        for (int reg = 0; reg < 4; ++reg) {
            const int r = row0 + (wave >> 1) * 16 + (lane >> 4) * 4 + reg;
            const int n = col0 + (wave & 1) * 16 + (lane & 15);
            out[(size_t)r * N + n] = acc[0][reg] + bias[n];
        }
    }
}

// ---------------------------------------------------------------------------
// Register-resident dense-score top-k attention (round-6 verified).
// 512 blocks x 4 waves; LDS = 16KB score/prob matrix only.
// ---------------------------------------------------------------------------
__global__ __launch_bounds__(256)
void attn_reg16_kernel(const _Float16* __restrict__ qh, const _Float16* __restrict__ kh,
                       const _Float16* __restrict__ vt, const int* __restrict__ topk,
                       const float* __restrict__ ontk, _Float16* __restrict__ attnh)
{
    __shared__ __align__(16) float Ps[QT * 256];   // 16 KB

    const int tid  = threadIdx.x;
    const int w    = tid >> 6;
    const int lane = tid & 63;
    const int bid  = blockIdx.x;
    const int bt   = bid >> 8;
    const int head = (bid >> 4) & 15;
    const int s0   = (bid & 15) * QT;
    const int bh   = bt * NH + head;

    // Q a-frags / K b-frags first (phase-A critical path)
    half8 aq[2], bk[2][4];
#pragma unroll
    for (int kk = 0; kk < 2; ++kk) {
        const int c8 = (kk * 4 + (lane >> 4)) * 8;
        aq[kk] = *(const half8*)(qh + ((size_t)bh * SEQ + s0 + (lane & 15)) * DH + c8);
#pragma unroll
        for (int j = 0; j < 4; ++j)
            bk[kk][j] = *(const half8*)(kh + ((size_t)bh * SEQ + w * 64 + j * 16 + (lane & 15)) * DH + c8);
    }
    int ki0[4], ki1[4], ki2[4];
#pragma unroll
    for (int qq = 0; qq < 4; ++qq) {
        const int* idxp = topk + ((size_t)bh * SEQ + s0 + w * 4 + qq) * KTOP;
        ki0[qq] = idxp[lane];
        ki1[qq] = idxp[lane + 64];
        ki2[qq] = idxp[(lane < 16) ? (lane + 128) : lane];
    }
    half8 bv[8];
    {
        const _Float16* vrow = vt + ((size_t)bh * DH + w * 16 + (lane & 15)) * SEQ
                                  + (lane >> 4) * 8;
#pragma unroll
        for (int ks = 0; ks < 8; ++ks)
            bv[ks] = *(const half8*)(vrow + ks * 32);
    }
    float on[4];
#pragma unroll
    for (int reg = 0; reg < 4; ++reg) {
        const int row = (lane >> 4) * 4 + reg;
        on[reg] = ontk[((size_t)bh * SEQ + s0 + row) * DH + w * 16 + (lane & 15)];
    }

    // Phase A: S[16][256]
    f32x4 acc[4] = {};
#pragma unroll
    for (int kk = 0; kk < 2; ++kk)
#pragma unroll
        for (int j = 0; j < 4; ++j)
            acc[j] = __builtin_amdgcn_mfma_f32_16x16x32_f16(aq[kk], bk[kk][j], acc[j], 0, 0, 0);
#pragma unroll
    for (int j = 0; j < 4; ++j)
#pragma unroll
        for (int reg = 0; reg < 4; ++reg) {
            const int row = (lane >> 4) * 4 + reg;
            const int col = w * 64 + j * 16 + (lane & 15);
            Ps[row * 256 + (col ^ ((row & 7) << 2))] = acc[j][reg];
        }
    __syncthreads();

    // Phase B: softmax + prob scatter (atomicAdd sums duplicate indices)
#pragma unroll
    for (int qq = 0; qq < 4; ++qq) {
        const int q  = w * 4 + qq;
        const int sw = (q & 7) << 2;
        float* prow  = Ps + q * 256;
        const float sv0 = prow[ki0[qq] ^ sw] * 0.125f;
        const float sv1 = prow[ki1[qq] ^ sw] * 0.125f;
        const float sv2 = (lane < 16) ? prow[ki2[qq] ^ sw] * 0.125f : -1e30f;
        float m = fmaxf(fmaxf(sv0, sv1), sv2);
#pragma unroll
        for (int off = 32; off; off >>= 1) m = fmaxf(m, __shfl_xor(m, off));
        const float e0 = __expf(sv0 - m);
        const float e1 = __expf(sv1 - m);
        const float e2 = (lane < 16) ? __expf(sv2 - m) : 0.f;
        float z = e0 + e1 + e2;
#pragma unroll
        for (int off = 32; off; off >>= 1) z += __shfl_xor(z, off);
        const float inv = 1.f / z;
#pragma unroll
        for (int c2 = 0; c2 < 4; ++c2) prow[lane + c2 * 64] = 0.f;
        atomicAdd(&prow[ki0[qq] ^ sw], e0 * inv);
        atomicAdd(&prow[ki1[qq] ^ sw], e1 * inv);
        if (lane < 16) atomicAdd(&prow[ki2[qq] ^ sw], e2 * inv);
    }
    __syncthreads();

    // Phase C: out[16][64] = P.V ; wave w owns d-cols w*16..+15
    f32x4 oacc = {};
#pragma unroll
    for (int ks = 0; ks < 8; ++ks) {
        const int ra = lane & 15;
        const int b0 = ks * 32 + (lane >> 4) * 8;
        const int sw = (ra & 7) << 2;
        const float4 p0 = *(const float4*)(Ps + ra * 256 + (b0 ^ sw));
        const float4 p1 = *(const float4*)(Ps + ra * 256 + ((b0 + 4) ^ sw));
        half8 af;
        af[0] = (_Float16)p0.x; af[1] = (_Float16)p0.y;
        af[2] = (_Float16)p0.z; af[3] = (_Float16)p0.w;
        af[4] = (_Float16)p1.x; af[5] = (_Float16)p1.y;
        af[6] = (_Float16)p1.z; af[7] = (_Float16)p1.w;
        oacc = __builtin_amdgcn_mfma_f32_16x16x32_f16(af, bv[ks], oacc, 0, 0, 0);
    }
#pragma unroll
    for (int reg = 0; reg < 4; ++reg) {
        const int row = (lane >> 4) * 4 + reg;
        const int d   = w * 16 + (lane & 15);
        const int s   = s0 + row;
        attnh[((size_t)(bt * SEQ + s)) * DIMF + head * DH + d] = (_Float16)(oacc[reg] + on[reg]);
    }
}

// ---------------------------------------------------------------------------
extern "C" void kernel_launch(void* const* d_in, const int* in_sizes, int n_in,
                              void* d_out, int out_size, void* d_ws, size_t ws_size,
                              hipStream_t stream) {
    const float* x     = (const float*)d_in[0];
    const float* w_qkv = (const float*)d_in[1];
    const float* w_out = (const float*)d_in[2];
    const float* b_out = (const float*)d_in[3];
    const float* ontk  = (const float*)d_in[4];
    const int*   topk  = (const int*)d_in[5];
    float* out = (float*)d_out;

    const size_t QE = (size_t)BTN * NH * SEQ * DH;   // 524288

    _Float16* xh    = (_Float16*)d_ws;
    _Float16* wqh   = xh + 524288;
    _Float16* woh   = wqh + 3145728;
    _Float16* attnh = woh + 1048576;
    _Float16* qhb   = attnh + QE;
    _Float16* khb   = qhb + QE;
    _Float16* vtb   = khb + QE;

    // 1) fp32->fp16 inputs
    cvt3_kernel<<<(N0Q + N1Q + N2Q) / 256, 256, 0, stream>>>(x, w_qkv, w_out, xh, wqh, woh);

    // 2) qkv projection + RoPE (768 blocks = 3.0/CU, BK=256)
    gemm_k256_kernel<0><<<dim3(3072 / 64, 512 / 32), 256, 0, stream>>>(
        xh, wqh, 3072, qhb, khb, vtb, nullptr, nullptr);

    // 3) high-occupancy register-resident top-k attention (512 blocks)
    attn_reg16_kernel<<<BTN * NH * (SEQ / QT), 256, 0, stream>>>(
        qhb, khb, vtb, topk, ontk, attnh);

    // 4) output projection + bias (512 blocks = 2.0/CU, BK=256)
    gemm_k256_kernel<1><<<dim3(1024 / 32, 512 / 32), 256, 0, stream>>>(
        attnh, woh, 1024, nullptr, nullptr, nullptr, b_out, out);
}

// Round 14
// 41.310 us; speedup vs baseline: 1.3541x; 1.0038x over previous
//
#include <hip/hip_runtime.h>
#include <hip/hip_bf16.h>
#include <math.h>

// SpatialAxialAttention: B*T=2, H=W=16, dim=1024, HEADS=16, DIM_HEAD=64, K=144
#define BTN   2
#define NH    16
#define SEQ   256
#define DH    64
#define DIMF  1024
#define KTOP  144
#define QT    16
#define PI_F  3.14159265358979323846f

typedef _Float16 half8 __attribute__((ext_vector_type(8)));
typedef _Float16 half4v __attribute__((ext_vector_type(4)));
typedef float f32x4 __attribute__((ext_vector_type(4)));

#define GLDS(src, dst) __builtin_amdgcn_global_load_lds( \
        (const __attribute__((address_space(1))) void*)(src), \
        (__attribute__((address_space(3))) void*)(dst), 16, 0, 0)

// ---------------------------------------------------------------------------
// fp32 -> fp16 conversion for x, w_qkv, w_out
// ---------------------------------------------------------------------------
#define N0Q (524288 / 4)
#define N1Q (3145728 / 4)
#define N2Q (1048576 / 4)
__global__ __launch_bounds__(256)
void cvt3_kernel(const float* __restrict__ a, const float* __restrict__ b,
                 const float* __restrict__ c,
                 _Float16* __restrict__ da, _Float16* __restrict__ db,
                 _Float16* __restrict__ dc)
{
    int q = blockIdx.x * 256 + threadIdx.x;
    const float* s; _Float16* d; int off;
    if (q < N0Q)            { s = a; d = da; off = q; }
    else if (q < N0Q + N1Q) { s = b; d = db; off = q - N0Q; }
    else                    { s = c; d = dc; off = q - (N0Q + N1Q); }
    const float4 v = *(const float4*)(s + (size_t)off * 4);
    half4v h;
    h[0] = (_Float16)v.x; h[1] = (_Float16)v.y;
    h[2] = (_Float16)v.z; h[3] = (_Float16)v.w;
    *(half4v*)(d + (size_t)off * 4) = h;
}

// ---------------------------------------------------------------------------
// fp16 MFMA NT-GEMM, BK=256, small tiles for grid balance:
//   MODE 0: BM=32 x BN=64, grid (48,16)=768 blocks (3.0/CU, 48KB LDS).
//   MODE 1: BM=32 x BN=32, grid (32,16)=512 blocks (2.0/CU, 32KB LDS).
// Rows are 512B = 32x16B chunks; XOR swizzle chunk ^= row&15.
// MODE 0 epilogue NEW (R14): per-wave LDS transpose (reuse As) -> coalesced
// 16B stores. q/k: 2 lanes per s-row (32B runs); v: 4 lanes per d-row (64B
// runs). Replaces the 8-per-thread scattered 2B stores. Same math/rounding.
// MODE 1: +bias fp32 store (already 64B-coalesced per 16-lane group).
// ---------------------------------------------------------------------------
template <int MODE>
__global__ __launch_bounds__(256)
void gemm_k256_kernel(const _Float16* __restrict__ A, const _Float16* __restrict__ B,
                      int N,
                      _Float16* __restrict__ qb, _Float16* __restrict__ kb,
                      _Float16* __restrict__ vb,
                      const float* __restrict__ bias, float* __restrict__ out)
{
    constexpr int BN = (MODE == 0) ? 64 : 32;
    __shared__ __align__(16) _Float16 As[32 * 256];    // 16 KB
    __shared__ __align__(16) _Float16 Bs[BN * 256];    // 32/16 KB

    const int Kd   = DIMF;
    const int tid  = threadIdx.x;
    const int wave = tid >> 6;
    const int lane = tid & 63;
    const int row0 = blockIdx.y * 32;
    const int col0 = blockIdx.x * BN;
    const int rl2  = lane >> 5;     // row within 2-row staging group
    const int cl32 = lane & 31;     // 16B chunk within 512B row

    f32x4 acc[2] = {};

    for (int kt = 0; kt < 4; ++kt) {
        __syncthreads();
        // A: 32 rows x 256; wave w stages rows w*8..w*8+7 (4 GLDS, 2 rows each)
#pragma unroll
        for (int h = 0; h < 4; ++h) {
            const int rA = wave * 8 + h * 2 + rl2;
            GLDS(A + (size_t)(row0 + rA) * Kd + kt * 256 + ((cl32 ^ (rA & 15)) * 8),
                 As + (wave * 8 + h * 2) * 256);
        }
        // B: BN rows x 256; wave w stages BN/4 rows
#pragma unroll
        for (int h = 0; h < BN / 8; ++h) {
            const int rB = wave * (BN / 4) + h * 2 + rl2;
            GLDS(B + (size_t)(col0 + rB) * Kd + kt * 256 + ((cl32 ^ (rB & 15)) * 8),
                 Bs + (wave * (BN / 4) + h * 2) * 256);
        }
        __syncthreads();

#pragma unroll
        for (int kh = 0; kh < 8; ++kh) {
            const int g = kh * 4 + (lane >> 4);
            if (MODE == 0) {
                const int rb = wave * 16 + (lane & 15);
                const half8 b = *(const half8*)(Bs + rb * 256 + ((g ^ (rb & 15)) * 8));
#pragma unroll
                for (int i = 0; i < 2; ++i) {
                    const int ra = i * 16 + (lane & 15);
                    const half8 a = *(const half8*)(As + ra * 256 + ((g ^ (ra & 15)) * 8));
                    acc[i] = __builtin_amdgcn_mfma_f32_16x16x32_f16(a, b, acc[i], 0, 0, 0);
                }
            } else {
                const int ra = (wave >> 1) * 16 + (lane & 15);
                const int rb = (wave & 1) * 16 + (lane & 15);
                const half8 a = *(const half8*)(As + ra * 256 + ((g ^ (ra & 15)) * 8));
                const half8 b = *(const half8*)(Bs + rb * 256 + ((g ^ (rb & 15)) * 8));
                acc[0] = __builtin_amdgcn_mfma_f32_16x16x32_f16(a, b, acc[0], 0, 0, 0);
            }
        }
    }

    // C/D layout: col = lane&15, row = (lane>>4)*4 + reg
    if (MODE == 0) {
        // ---- coalesced epilogue via per-wave LDS transpose (reuse As) ----
        const int nbase = col0 + wave * 16;       // wave-uniform 16-col window
        const int sec   = nbase >> 10;            // 0=q,1=k,2=v (block/wave-uniform)
        const int head  = (nbase & 1023) >> 6;
        const int d0    = nbase & 63;             // 16-aligned
        const int bt    = row0 >> 8;
        const int sbase = row0 & 255;

        __syncthreads();                           // all waves done reading As/Bs

        if (sec != 2) {
            // q/k with RoPE: wave tile [32 s][24 pad] halves (rows 48B, 16B-aligned)
            _Float16* tile = As + wave * 768;
#pragma unroll
            for (int i = 0; i < 2; ++i) {
#pragma unroll
                for (int reg = 0; reg < 4; ++reg) {
                    const int srow = i * 16 + (lane >> 4) * 4 + reg;    // 0..31
                    const int s    = sbase + srow;
                    const int hh   = s >> 4;
                    const int ww   = s & 15;
                    const float v     = acc[i][reg];
                    const float other = __shfl_xor(v, 1);   // RoPE pair partner
                    const int d    = d0 + (lane & 15);
                    const int de   = d & ~1;
                    const int j2   = (de < 32) ? (de >> 1) : ((de - 32) >> 1);
                    const float pos = (de < 32) ? (-1.f + hh * (2.f / 15.f))
                                                : (-1.f + ww * (2.f / 15.f));
                    const float f  = pos * (PI_F * (1.f + j2 * (127.f / 15.f)));
                    const float cf = __cosf(f), sf = __sinf(f);
                    const float res = (d & 1) ? (v * cf + other * sf)
                                              : (v * cf - other * sf);
                    tile[srow * 24 + (lane & 15)] = (_Float16)res;
                }
            }
            // same-wave LDS write->read: compiler inserts lgkmcnt, no barrier
            const int srow = lane >> 1;           // 0..31
            const int part = lane & 1;
            const half8 o = *(const half8*)(tile + srow * 24 + part * 8);
            _Float16* dp = (sec == 0) ? qb : kb;
            *(half8*)(dp + (((size_t)(bt * NH + head)) * SEQ + sbase + srow) * DH
                      + d0 + part * 8) = o;
        } else {
            // v transposed (bt,head,d,s): wave tile [16 d][40 pad] halves
            _Float16* tv = As + 4096 + wave * 640;
#pragma unroll
            for (int i = 0; i < 2; ++i) {
#pragma unroll
                for (int reg = 0; reg < 4; ++reg) {
                    const int srow = i * 16 + (lane >> 4) * 4 + reg;    // 0..31
                    tv[(lane & 15) * 40 + srow] = (_Float16)acc[i][reg];
                }
            }
            const int didx = lane >> 2;           // 0..15
            const int q4   = lane & 3;
            const half8 o = *(const half8*)(tv + didx * 40 + q4 * 8);
            *(half8*)(vb + (((size_t)(bt * NH + head)) * DH + d0 + didx) * SEQ
                      + sbase + q4 * 8) = o;
        }
    } else {
#pragma unroll
        for (int reg = 0; reg < 4; ++reg) {
            const int r = row0 + (wave >> 1) * 16 + (lane >> 4) * 4 + reg;
            const int n = col0 + (wave & 1) * 16 + (lane & 15);
            out[(size_t)r * N + n] = acc[0][reg] + bias[n];
        }
    }
}

// ---------------------------------------------------------------------------
// Register-resident dense-score top-k attention (round-6 verified).
// 512 blocks x 4 waves; LDS = 16KB score/prob matrix only.
// ---------------------------------------------------------------------------
__global__ __launch_bounds__(256)
void attn_reg16_kernel(const _Float16* __restrict__ qh, const _Float16* __restrict__ kh,
                       const _Float16* __restrict__ vt, const int* __restrict__ topk,
                       const float* __restrict__ ontk, _Float16* __restrict__ attnh)
{
    __shared__ __align__(16) float Ps[QT * 256];   // 16 KB

    const int tid  = threadIdx.x;
    const int w    = tid >> 6;
    const int lane = tid & 63;
    const int bid  = blockIdx.x;
    const int bt   = bid >> 8;
    const int head = (bid >> 4) & 15;
    const int s0   = (bid & 15) * QT;
    const int bh   = bt * NH + head;

    // Q a-frags / K b-frags first (phase-A critical path)
    half8 aq[2], bk[2][4];
#pragma unroll
    for (int kk = 0; kk < 2; ++kk) {
        const int c8 = (kk * 4 + (lane >> 4)) * 8;
        aq[kk] = *(const half8*)(qh + ((size_t)bh * SEQ + s0 + (lane & 15)) * DH + c8);
#pragma unroll
        for (int j = 0; j < 4; ++j)
            bk[kk][j] = *(const half8*)(kh + ((size_t)bh * SEQ + w * 64 + j * 16 + (lane & 15)) * DH + c8);
    }
    int ki0[4], ki1[4], ki2[4];
#pragma unroll
    for (int qq = 0; qq < 4; ++qq) {
        const int* idxp = topk + ((size_t)bh * SEQ + s0 + w * 4 + qq) * KTOP;
        ki0[qq] = idxp[lane];
        ki1[qq] = idxp[lane + 64];
        ki2[qq] = idxp[(lane < 16) ? (lane + 128) : lane];
    }
    half8 bv[8];
    {
        const _Float16* vrow = vt + ((size_t)bh * DH + w * 16 + (lane & 15)) * SEQ
                                  + (lane >> 4) * 8;
#pragma unroll
        for (int ks = 0; ks < 8; ++ks)
            bv[ks] = *(const half8*)(vrow + ks * 32);
    }
    float on[4];
#pragma unroll
    for (int reg = 0; reg < 4; ++reg) {
        const int row = (lane >> 4) * 4 + reg;
        on[reg] = ontk[((size_t)bh * SEQ + s0 + row) * DH + w * 16 + (lane & 15)];
    }

    // Phase A: S[16][256]
    f32x4 acc[4] = {};
#pragma unroll
    for (int kk = 0; kk < 2; ++kk)
#pragma unroll
        for (int j = 0; j < 4; ++j)
            acc[j] = __builtin_amdgcn_mfma_f32_16x16x32_f16(aq[kk], bk[kk][j], acc[j], 0, 0, 0);
#pragma unroll
    for (int j = 0; j < 4; ++j)
#pragma unroll
        for (int reg = 0; reg < 4; ++reg) {
            const int row = (lane >> 4) * 4 + reg;
            const int col = w * 64 + j * 16 + (lane & 15);
            Ps[row * 256 + (col ^ ((row & 7) << 2))] = acc[j][reg];
        }
    __syncthreads();

    // Phase B: softmax + prob scatter (atomicAdd sums duplicate indices)
#pragma unroll
    for (int qq = 0; qq < 4; ++qq) {
        const int q  = w * 4 + qq;
        const int sw = (q & 7) << 2;
        float* prow  = Ps + q * 256;
        const float sv0 = prow[ki0[qq] ^ sw] * 0.125f;
        const float sv1 = prow[ki1[qq] ^ sw] * 0.125f;
        const float sv2 = (lane < 16) ? prow[ki2[qq] ^ sw] * 0.125f : -1e30f;
        float m = fmaxf(fmaxf(sv0, sv1), sv2);
#pragma unroll
        for (int off = 32; off; off >>= 1) m = fmaxf(m, __shfl_xor(m, off));
        const float e0 = __expf(sv0 - m);
        const float e1 = __expf(sv1 - m);
        const float e2 = (lane < 16) ? __expf(sv2 - m) : 0.f;
        float z = e0 + e1 + e2;
#pragma unroll
        for (int off = 32; off; off >>= 1) z += __shfl_xor(z, off);
        const float inv = 1.f / z;
#pragma unroll
        for (int c2 = 0; c2 < 4; ++c2) prow[lane + c2 * 64] = 0.f;
        atomicAdd(&prow[ki0[qq] ^ sw], e0 * inv);
        atomicAdd(&prow[ki1[qq] ^ sw], e1 * inv);
        if (lane < 16) atomicAdd(&prow[ki2[qq] ^ sw], e2 * inv);
    }
    __syncthreads();

    // Phase C: out[16][64] = P.V ; wave w owns d-cols w*16..+15
    f32x4 oacc = {};
#pragma unroll
    for (int ks = 0; ks < 8; ++ks) {
        const int ra = lane & 15;
        const int b0 = ks * 32 + (lane >> 4) * 8;
        const int sw = (ra & 7) << 2;
        const float4 p0 = *(const float4*)(Ps + ra * 256 + (b0 ^ sw));
        const float4 p1 = *(const float4*)(Ps + ra * 256 + ((b0 + 4) ^ sw));
        half8 af;
        af[0] = (_Float16)p0.x; af[1] = (_Float16)p0.y;
        af[2] = (_Float16)p0.z; af[3] = (_Float16)p0.w;
        af[4] = (_Float16)p1.x; af[5] = (_Float16)p1.y;
        af[6] = (_Float16)p1.z; af[7] = (_Float16)p1.w;
        oacc = __builtin_amdgcn_mfma_f32_16x16x32_f16(af, bv[ks], oacc, 0, 0, 0);
    }
#pragma unroll
    for (int reg = 0; reg < 4; ++reg) {
        const int row = (lane >> 4) * 4 + reg;
        const int d   = w * 16 + (lane & 15);
        const int s   = s0 + row;
        attnh[((size_t)(bt * SEQ + s)) * DIMF + head * DH + d] = (_Float16)(oacc[reg] + on[reg]);
    }
}

// ---------------------------------------------------------------------------
extern "C" void kernel_launch(void* const* d_in, const int* in_sizes, int n_in,
                              void* d_out, int out_size, void* d_ws, size_t ws_size,
                              hipStream_t stream) {
    const float* x     = (const float*)d_in[0];
    const float* w_qkv = (const float*)d_in[1];
    const float* w_out = (const float*)d_in[2];
    const float* b_out = (const float*)d_in[3];
    const float* ontk  = (const float*)d_in[4];
    const int*   topk  = (const int*)d_in[5];
    float* out = (float*)d_out;

    const size_t QE = (size_t)BTN * NH * SEQ * DH;   // 524288

    _Float16* xh    = (_Float16*)d_ws;
    _Float16* wqh   = xh + 524288;
    _Float16* woh   = wqh + 3145728;
    _Float16* attnh = woh + 1048576;
    _Float16* qhb   = attnh + QE;
    _Float16* khb   = qhb + QE;
    _Float16* vtb   = khb + QE;

    // 1) fp32->fp16 inputs
    cvt3_kernel<<<(N0Q + N1Q + N2Q) / 256, 256, 0, stream>>>(x, w_qkv, w_out, xh, wqh, woh);

    // 2) qkv projection + RoPE (768 blocks = 3.0/CU, BK=256, coalesced epilogue)
    gemm_k256_kernel<0><<<dim3(3072 / 64, 512 / 32), 256, 0, stream>>>(
        xh, wqh, 3072, qhb, khb, vtb, nullptr, nullptr);

    // 3) high-occupancy register-resident top-k attention (512 blocks)
    attn_reg16_kernel<<<BTN * NH * (SEQ / QT), 256, 0, stream>>>(
        qhb, khb, vtb, topk, ontk, attnh);

    // 4) output projection + bias (512 blocks = 2.0/CU, BK=256)
    gemm_k256_kernel<1><<<dim3(1024 / 32, 512 / 32), 256, 0, stream>>>(
        attnh, woh, 1024, nullptr, nullptr, nullptr, b_out, out);
}

// Round 16
// 40.135 us; speedup vs baseline: 1.3938x; 1.0293x over previous
//
#include <hip/hip_runtime.h>
#include <hip/hip_bf16.h>
#include <math.h>

// SpatialAxialAttention: B*T=2, H=W=16, dim=1024, HEADS=16, DIM_HEAD=64, K=144
#define BTN   2
#define NH    16
#define SEQ   256
#define DH    64
#define DIMF  1024
#define KTOP  144
#define QT    16
#define PI_F  3.14159265358979323846f

typedef _Float16 half8 __attribute__((ext_vector_type(8)));
typedef _Float16 half4v __attribute__((ext_vector_type(4)));
typedef float f32x4 __attribute__((ext_vector_type(4)));

#define GLDS(src, dst) __builtin_amdgcn_global_load_lds( \
        (const __attribute__((address_space(1))) void*)(src), \
        (__attribute__((address_space(3))) void*)(dst), 16, 0, 0)

// ---------------------------------------------------------------------------
// fp32 -> fp16 conversion for x, w_qkv, w_out
// ---------------------------------------------------------------------------
#define N0Q (524288 / 4)
#define N1Q (3145728 / 4)
#define N2Q (1048576 / 4)
__global__ __launch_bounds__(256)
void cvt3_kernel(const float* __restrict__ a, const float* __restrict__ b,
                 const float* __restrict__ c,
                 _Float16* __restrict__ da, _Float16* __restrict__ db,
                 _Float16* __restrict__ dc)
{
    int q = blockIdx.x * 256 + threadIdx.x;
    const float* s; _Float16* d; int off;
    if (q < N0Q)            { s = a; d = da; off = q; }
    else if (q < N0Q + N1Q) { s = b; d = db; off = q - N0Q; }
    else                    { s = c; d = dc; off = q - (N0Q + N1Q); }
    const float4 v = *(const float4*)(s + (size_t)off * 4);
    half4v h;
    h[0] = (_Float16)v.x; h[1] = (_Float16)v.y;
    h[2] = (_Float16)v.z; h[3] = (_Float16)v.w;
    *(half4v*)(d + (size_t)off * 4) = h;
}

// ---------------------------------------------------------------------------
// QKV GEMM, 8-wave: BM=32 x BN=64, BK=256, 512 threads, 48KB LDS.
// Per-wave chain: 1 frag, 32 MFMA, 6 GLDS; 3 blocks/CU x 8 waves = 24 w/CU.
// Wave w: output rows (w>>2)*16..+15, cols (w&3)*16..+15 of the 32x64 tile.
// Rows 512B = 32x16B chunks; XOR swizzle chunk ^= row&15 (pre-swizzled
// global source, linear LDS dest). Coalesced epilogue via per-wave LDS
// transpose (reuse As): q/k RoPE'd -> (bt,head,s,d); v -> (bt,head,d,s).
// ---------------------------------------------------------------------------
__global__ __launch_bounds__(512)
void gemm_qkv_w8_kernel(const _Float16* __restrict__ A, const _Float16* __restrict__ B,
                        _Float16* __restrict__ qb, _Float16* __restrict__ kb,
                        _Float16* __restrict__ vb)
{
    __shared__ __align__(16) _Float16 As[32 * 256];    // 16 KB
    __shared__ __align__(16) _Float16 Bs[64 * 256];    // 32 KB

    const int Kd   = DIMF;
    const int tid  = threadIdx.x;
    const int wave = tid >> 6;      // 0..7
    const int lane = tid & 63;
    const int row0 = blockIdx.y * 32;
    const int col0 = blockIdx.x * 64;
    const int rq   = wave >> 2;     // row quadrant (0/1)
    const int cq   = wave & 3;      // col quadrant (0..3)
    const int rl2  = lane >> 5;     // row within 2-row staging group
    const int cl32 = lane & 31;     // 16B chunk within 512B row

    f32x4 acc = {};

    for (int kt = 0; kt < 4; ++kt) {
        __syncthreads();
        // A: 32 rows; wave w stages rows w*4..w*4+3 (2 GLDS, 2 rows each)
#pragma unroll
        for (int h = 0; h < 2; ++h) {
            const int rA = wave * 4 + h * 2 + rl2;
            GLDS(A + (size_t)(row0 + rA) * Kd + kt * 256 + ((cl32 ^ (rA & 15)) * 8),
                 As + (wave * 4 + h * 2) * 256);
        }
        // B: 64 rows; wave w stages rows w*8..w*8+7 (4 GLDS)
#pragma unroll
        for (int h = 0; h < 4; ++h) {
            const int rB = wave * 8 + h * 2 + rl2;
            GLDS(B + (size_t)(col0 + rB) * Kd + kt * 256 + ((cl32 ^ (rB & 15)) * 8),
                 Bs + (wave * 8 + h * 2) * 256);
        }
        __syncthreads();

#pragma unroll
        for (int kh = 0; kh < 8; ++kh) {
            const int g  = kh * 4 + (lane >> 4);
            const int ra = rq * 16 + (lane & 15);
            const int rb = cq * 16 + (lane & 15);
            const half8 a = *(const half8*)(As + ra * 256 + ((g ^ (ra & 15)) * 8));
            const half8 b = *(const half8*)(Bs + rb * 256 + ((g ^ (rb & 15)) * 8));
            acc = __builtin_amdgcn_mfma_f32_16x16x32_f16(a, b, acc, 0, 0, 0);
        }
    }

    // ---- coalesced epilogue via per-wave LDS transpose (reuse As) ----
    // C/D layout: col = lane&15, row = (lane>>4)*4 + reg (local 16x16 frag)
    const int nbase = col0 + cq * 16;         // wave-uniform 16-col window
    const int sec   = nbase >> 10;            // 0=q,1=k,2=v (wave-uniform)
    const int head  = (nbase & 1023) >> 6;
    const int d0    = nbase & 63;             // 16-aligned
    const int bt    = row0 >> 8;
    const int sbase = (row0 & 255) + rq * 16; // 16-aligned s base for this wave

    __syncthreads();                           // all waves done reading As/Bs

    _Float16* tile = As + wave * 384;          // [16][24] halves per wave

    if (sec != 2) {
        // q/k with RoPE: tile[s_local][d_local]
#pragma unroll
        for (int reg = 0; reg < 4; ++reg) {
            const int sl = (lane >> 4) * 4 + reg;      // 0..15
            const int s  = sbase + sl;
            const int hh = s >> 4;
            const int ww = s & 15;
            const float v     = acc[reg];
            const float other = __shfl_xor(v, 1);      // RoPE pair partner
            const int d  = d0 + (lane & 15);
            const int de = d & ~1;
            const int j2 = (de < 32) ? (de >> 1) : ((de - 32) >> 1);
            const float pos = (de < 32) ? (-1.f + hh * (2.f / 15.f))
                                        : (-1.f + ww * (2.f / 15.f));
            const float f  = pos * (PI_F * (1.f + j2 * (127.f / 15.f)));
            const float cf = __cosf(f), sf = __sinf(f);
            const float res = (d & 1) ? (v * cf + other * sf)
                                      : (v * cf - other * sf);
            tile[sl * 24 + (lane & 15)] = (_Float16)res;
        }
        // same-wave LDS write->read (compiler inserts lgkmcnt)
        if (lane < 32) {
            const int sl   = lane >> 1;
            const int part = lane & 1;
            const half8 o = *(const half8*)(tile + sl * 24 + part * 8);
            _Float16* dp = (sec == 0) ? qb : kb;
            *(half8*)(dp + (((size_t)(bt * NH + head)) * SEQ + sbase + sl) * DH
                      + d0 + part * 8) = o;
        }
    } else {
        // v transposed: tile[d_local][s_local]
#pragma unroll
        for (int reg = 0; reg < 4; ++reg) {
            const int sl = (lane >> 4) * 4 + reg;      // 0..15
            tile[(lane & 15) * 24 + sl] = (_Float16)acc[reg];
        }
        if (lane < 32) {
            const int dl   = lane >> 1;                // 0..15
            const int part = lane & 1;
            const half8 o = *(const half8*)(tile + dl * 24 + part * 8);
            *(half8*)(vb + (((size_t)(bt * NH + head)) * DH + d0 + dl) * SEQ
                      + sbase + part * 8) = o;
        }
    }
}

// ---------------------------------------------------------------------------
// Out-projection GEMM (R13 verified): BM=32 x BN=32, BK=256, 256 threads,
// grid (32,16)=512 blocks (2.0/CU, 32KB LDS). +bias fp32 store.
// R16 FIX: B staging is 4 GLDS/wave (h<4), staging all 32 rows — R15's h<2
// left half of Bs uninitialized (the NaN source).
// ---------------------------------------------------------------------------
__global__ __launch_bounds__(256)
void gemm_out_kernel(const _Float16* __restrict__ A, const _Float16* __restrict__ B,
                     const float* __restrict__ bias, float* __restrict__ out)
{
    __shared__ __align__(16) _Float16 As[32 * 256];    // 16 KB
    __shared__ __align__(16) _Float16 Bs[32 * 256];    // 16 KB

    const int Kd   = DIMF;
    const int tid  = threadIdx.x;
    const int wave = tid >> 6;
    const int lane = tid & 63;
    const int row0 = blockIdx.y * 32;
    const int col0 = blockIdx.x * 32;
    const int rl2  = lane >> 5;
    const int cl32 = lane & 31;

    f32x4 acc = {};

    for (int kt = 0; kt < 4; ++kt) {
        __syncthreads();
#pragma unroll
        for (int h = 0; h < 4; ++h) {
            const int rA = wave * 8 + h * 2 + rl2;
            GLDS(A + (size_t)(row0 + rA) * Kd + kt * 256 + ((cl32 ^ (rA & 15)) * 8),
                 As + (wave * 8 + h * 2) * 256);
        }
#pragma unroll
        for (int h = 0; h < 4; ++h) {
            const int rB = wave * 8 + h * 2 + rl2;
            GLDS(B + (size_t)(col0 + rB) * Kd + kt * 256 + ((cl32 ^ (rB & 15)) * 8),
                 Bs + (wave * 8 + h * 2) * 256);
        }
        __syncthreads();

#pragma unroll
        for (int kh = 0; kh < 8; ++kh) {
            const int g  = kh * 4 + (lane >> 4);
            const int ra = (wave >> 1) * 16 + (lane & 15);
            const int rb = (wave & 1) * 16 + (lane & 15);
            const half8 a = *(const half8*)(As + ra * 256 + ((g ^ (ra & 15)) * 8));
            const half8 b = *(const half8*)(Bs + rb * 256 + ((g ^ (rb & 15)) * 8));
            acc = __builtin_amdgcn_mfma_f32_16x16x32_f16(a, b, acc, 0, 0, 0);
        }
    }

#pragma unroll
    for (int reg = 0; reg < 4; ++reg) {
        const int r = row0 + (wave >> 1) * 16 + (lane >> 4) * 4 + reg;
        const int n = col0 + (wave & 1) * 16 + (lane & 15);
        out[(size_t)r * DIMF + n] = acc[reg] + bias[n];
    }
}

// ---------------------------------------------------------------------------
// Register-resident dense-score top-k attention (round-6 verified).
// 512 blocks x 4 waves; LDS = 16KB score/prob matrix only.
// ---------------------------------------------------------------------------
__global__ __launch_bounds__(256)
void attn_reg16_kernel(const _Float16* __restrict__ qh, const _Float16* __restrict__ kh,
                       const _Float16* __restrict__ vt, const int* __restrict__ topk,
                       const float* __restrict__ ontk, _Float16* __restrict__ attnh)
{
    __shared__ __align__(16) float Ps[QT * 256];   // 16 KB

    const int tid  = threadIdx.x;
    const int w    = tid >> 6;
    const int lane = tid & 63;
    const int bid  = blockIdx.x;
    const int bt   = bid >> 8;
    const int head = (bid >> 4) & 15;
    const int s0   = (bid & 15) * QT;
    const int bh   = bt * NH + head;

    // Q a-frags / K b-frags first (phase-A critical path)
    half8 aq[2], bk[2][4];
#pragma unroll
    for (int kk = 0; kk < 2; ++kk) {
        const int c8 = (kk * 4 + (lane >> 4)) * 8;
        aq[kk] = *(const half8*)(qh + ((size_t)bh * SEQ + s0 + (lane & 15)) * DH + c8);
#pragma unroll
        for (int j = 0; j < 4; ++j)
            bk[kk][j] = *(const half8*)(kh + ((size_t)bh * SEQ + w * 64 + j * 16 + (lane & 15)) * DH + c8);
    }
    int ki0[4], ki1[4], ki2[4];
#pragma unroll
    for (int qq = 0; qq < 4; ++qq) {
        const int* idxp = topk + ((size_t)bh * SEQ + s0 + w * 4 + qq) * KTOP;
        ki0[qq] = idxp[lane];
        ki1[qq] = idxp[lane + 64];
        ki2[qq] = idxp[(lane < 16) ? (lane + 128) : lane];
    }
    half8 bv[8];
    {
        const _Float16* vrow = vt + ((size_t)bh * DH + w * 16 + (lane & 15)) * SEQ
                                  + (lane >> 4) * 8;
#pragma unroll
        for (int ks = 0; ks < 8; ++ks)
            bv[ks] = *(const half8*)(vrow + ks * 32);
    }
    float on[4];
#pragma unroll
    for (int reg = 0; reg < 4; ++reg) {
        const int row = (lane >> 4) * 4 + reg;
        on[reg] = ontk[((size_t)bh * SEQ + s0 + row) * DH + w * 16 + (lane & 15)];
    }

    // Phase A: S[16][256]
    f32x4 acc[4] = {};
#pragma unroll
    for (int kk = 0; kk < 2; ++kk)
#pragma unroll
        for (int j = 0; j < 4; ++j)
            acc[j] = __builtin_amdgcn_mfma_f32_16x16x32_f16(aq[kk], bk[kk][j], acc[j], 0, 0, 0);
#pragma unroll
    for (int j = 0; j < 4; ++j)
#pragma unroll
        for (int reg = 0; reg < 4; ++reg) {
            const int row = (lane >> 4) * 4 + reg;
            const int col = w * 64 + j * 16 + (lane & 15);
            Ps[row * 256 + (col ^ ((row & 7) << 2))] = acc[j][reg];
        }
    __syncthreads();

    // Phase B: softmax + prob scatter (atomicAdd sums duplicate indices)
#pragma unroll
    for (int qq = 0; qq < 4; ++qq) {
        const int q  = w * 4 + qq;
        const int sw = (q & 7) << 2;
        float* prow  = Ps + q * 256;
        const float sv0 = prow[ki0[qq] ^ sw] * 0.125f;
        const float sv1 = prow[ki1[qq] ^ sw] * 0.125f;
        const float sv2 = (lane < 16) ? prow[ki2[qq] ^ sw] * 0.125f : -1e30f;
        float m = fmaxf(fmaxf(sv0, sv1), sv2);
#pragma unroll
        for (int off = 32; off; off >>= 1) m = fmaxf(m, __shfl_xor(m, off));
        const float e0 = __expf(sv0 - m);
        const float e1 = __expf(sv1 - m);
        const float e2 = (lane < 16) ? __expf(sv2 - m) : 0.f;
        float z = e0 + e1 + e2;
#pragma unroll
        for (int off = 32; off; off >>= 1) z += __shfl_xor(z, off);
        const float inv = 1.f / z;
#pragma unroll
        for (int c2 = 0; c2 < 4; ++c2) prow[lane + c2 * 64] = 0.f;
        atomicAdd(&prow[ki0[qq] ^ sw], e0 * inv);
        atomicAdd(&prow[ki1[qq] ^ sw], e1 * inv);
        if (lane < 16) atomicAdd(&prow[ki2[qq] ^ sw], e2 * inv);
    }
    __syncthreads();

    // Phase C: out[16][64] = P.V ; wave w owns d-cols w*16..+15
    f32x4 oacc = {};
#pragma unroll
    for (int ks = 0; ks < 8; ++ks) {
        const int ra = lane & 15;
        const int b0 = ks * 32 + (lane >> 4) * 8;
        const int sw = (ra & 7) << 2;
        const float4 p0 = *(const float4*)(Ps + ra * 256 + (b0 ^ sw));
        const float4 p1 = *(const float4*)(Ps + ra * 256 + ((b0 + 4) ^ sw));
        half8 af;
        af[0] = (_Float16)p0.x; af[1] = (_Float16)p0.y;
        af[2] = (_Float16)p0.z; af[3] = (_Float16)p0.w;
        af[4] = (_Float16)p1.x; af[5] = (_Float16)p1.y;
        af[6] = (_Float16)p1.z; af[7] = (_Float16)p1.w;
        oacc = __builtin_amdgcn_mfma_f32_16x16x32_f16(af, bv[ks], oacc, 0, 0, 0);
    }
#pragma unroll
    for (int reg = 0; reg < 4; ++reg) {
        const int row = (lane >> 4) * 4 + reg;
        const int d   = w * 16 + (lane & 15);
        const int s   = s0 + row;
        attnh[((size_t)(bt * SEQ + s)) * DIMF + head * DH + d] = (_Float16)(oacc[reg] + on[reg]);
    }
}

// ---------------------------------------------------------------------------
extern "C" void kernel_launch(void* const* d_in, const int* in_sizes, int n_in,
                              void* d_out, int out_size, void* d_ws, size_t ws_size,
                              hipStream_t stream) {
    const float* x     = (const float*)d_in[0];
    const float* w_qkv = (const float*)d_in[1];
    const float* w_out = (const float*)d_in[2];
    const float* b_out = (const float*)d_in[3];
    const float* ontk  = (const float*)d_in[4];
    const int*   topk  = (const int*)d_in[5];
    float* out = (float*)d_out;

    const size_t QE = (size_t)BTN * NH * SEQ * DH;   // 524288

    _Float16* xh    = (_Float16*)d_ws;
    _Float16* wqh   = xh + 524288;
    _Float16* woh   = wqh + 3145728;
    _Float16* attnh = woh + 1048576;
    _Float16* qhb   = attnh + QE;
    _Float16* khb   = qhb + QE;
    _Float16* vtb   = khb + QE;

    // 1) fp32->fp16 inputs
    cvt3_kernel<<<(N0Q + N1Q + N2Q) / 256, 256, 0, stream>>>(x, w_qkv, w_out, xh, wqh, woh);

    // 2) qkv projection + RoPE (768 blocks x 512 thr = 24 waves/CU)
    gemm_qkv_w8_kernel<<<dim3(3072 / 64, 512 / 32), 512, 0, stream>>>(
        xh, wqh, qhb, khb, vtb);

    // 3) high-occupancy register-resident top-k attention (512 blocks)
    attn_reg16_kernel<<<BTN * NH * (SEQ / QT), 256, 0, stream>>>(
        qhb, khb, vtb, topk, ontk, attnh);

    // 4) output projection + bias (512 blocks = 2.0/CU, BK=256)
    gemm_out_kernel<<<dim3(1024 / 32, 512 / 32), 256, 0, stream>>>(
        attnh, woh, b_out, out);
}